// Round 3
// baseline (263.869 us; speedup 1.0000x reference)
//
#include <hip/hip_runtime.h>
#include <hip/hip_bf16.h>
#include <cstdint>

// Problem constants (from reference)
#define T_  4
#define B_  32
#define C_  384
#define HF_ 1536
#define HW_ 196
#define E_  8
#define N_  128           // T*B
#define REC_CAP 16384

#define LIFB (B_ * C_)        // 12288 lif blocks
#define TRB  (E_ * 12 * 24)   // 2304 transpose blocks
#define PRB  48               // prep blocks

// ---------------------------------------------------------------------------
// K1 (fused): LIF spike counts + BN-const folding + w1 transpose->bf16
// ---------------------------------------------------------------------------
__global__ __launch_bounds__(256) void k_lifprep(
    const float* __restrict__ x, float* __restrict__ cnt,
    const float* __restrict__ w1, __hip_bfloat16* __restrict__ w1t,
    const float* b1, const float* g1, const float* be1,
    const float* m1, const float* v1,
    const float* b2, const float* g2, const float* be2,
    const float* m2, const float* v2,
    const float* taus,
    float* A, float* Bc, float* const2, float* inv2v,
    int* header) {
  __shared__ float tile[64][33];
  __shared__ int c4[T_];
  int blk = blockIdx.x;
  int tid = threadIdx.x;

  if (blk < LIFB) {
    // ---- LIF ----
    if (tid < T_) c4[tid] = 0;
    __syncthreads();
    int bc = blk;
    bool act = tid < HW_;
    float v = 0.f;
    size_t base = (size_t)bc * HW_ + (act ? tid : 0);
    #pragma unroll
    for (int t = 0; t < T_; ++t) {
      float xv = act ? x[base + (size_t)t * B_ * C_ * HW_] : -1e30f;
      v = v + (xv - v) * 0.5f;                 // tau=2.0 exactly
      bool sp = (v - 1.0f >= 0.0f);
      if (sp) v = 0.f;
      unsigned long long m = __ballot(act && sp);
      if ((tid & 63) == 0) atomicAdd(&c4[t], __popcll(m));
    }
    __syncthreads();
    if (tid < T_) cnt[(size_t)tid * B_ * C_ + bc] = (float)c4[tid];
  } else if (blk < LIFB + TRB) {
    // ---- transpose w1 -> bf16 w1t ----
    int rem = blk - LIFB;
    int e = rem / 288, r2 = rem % 288;
    int ct = r2 / 24, ot = r2 % 24;
    int c0 = ct * 32, o0 = ot * 64;
    int cl = tid & 31, olb = tid >> 5;
    #pragma unroll
    for (int it = 0; it < 8; ++it) {
      int ol = olb + it * 8;
      tile[ol][cl] = w1[(size_t)(e * HF_ + o0 + ol) * C_ + c0 + cl];
    }
    __syncthreads();
    int ol2 = tid & 63, clb = tid >> 6;
    #pragma unroll
    for (int it = 0; it < 8; ++it) {
      int cl2 = clb + it * 4;
      w1t[(size_t)(e * C_ + c0 + cl2) * HF_ + o0 + ol2] =
          __float2bfloat16(tile[ol2][cl2]);
    }
  } else {
    // ---- prep ----
    int idx = (blk - LIFB - TRB) * 256 + tid;
    if (idx < 64) header[idx] = 0;
    if (idx < E_ * HF_) {
      int e = idx / HF_;
      float inv = g1[idx] / sqrtf(v1[idx] + 1e-5f);
      float sh  = be1[idx] - m1[idx] * inv;
      A[idx]  = inv;
      Bc[idx] = inv * b1[idx] + sh - taus[e];
    }
    if (idx < E_ * C_) {
      float inv = g2[idx] / sqrtf(v2[idx] + 1e-5f);
      const2[idx] = b2[idx] * inv + (be2[idx] - m2[idx] * inv);
      inv2v[idx]  = inv;
    }
  }
}

// ---------------------------------------------------------------------------
// K2: router logits -> softmax -> top-2 -> gate; aux accumulators; K[n,c]
// ---------------------------------------------------------------------------
__global__ void k_router(const float* __restrict__ cnt, const float* __restrict__ rw,
                         const float* rb, const float* rg, const float* rbeta,
                         const float* rmean, const float* rvar,
                         const float* __restrict__ const2,
                         int* sel_e, float* sel_g, float* gsum, float* K,
                         float* f_acc, float* p_acc) {
  __shared__ float sc[C_];
  __shared__ float part[64];
  __shared__ float lg[E_];
  __shared__ int s_i1, s_i2;
  __shared__ float s_g1, s_g2;
  int n = blockIdx.x, tid = threadIdx.x;  // 64 threads
  for (int c = tid; c < C_; c += 64) sc[c] = cnt[(size_t)n * C_ + c];
  __syncthreads();
  {
    int e = tid & 7, pp = tid >> 3;
    float d = 0.f;
    for (int c = pp * 48; c < pp * 48 + 48; ++c) d += rw[e * C_ + c] * sc[c];
    part[pp * 8 + e] = d;
  }
  __syncthreads();
  if (tid < E_) {
    float dot = 0.f;
    for (int p = 0; p < 8; ++p) dot += part[p * 8 + tid];
    float inv = rg[tid] / sqrtf(rvar[tid] + 1e-5f);
    lg[tid] = (dot * (1.0f / HW_) + rb[tid]) * inv + (rbeta[tid] - rmean[tid] * inv);
  }
  __syncthreads();
  if (tid == 0) {
    float m = lg[0];
    for (int e = 1; e < E_; ++e) m = fmaxf(m, lg[e]);
    float p[E_]; float s = 0.f;
    for (int e = 0; e < E_; ++e) { p[e] = expf(lg[e] - m); s += p[e]; }
    float invs = 1.0f / s;
    for (int e = 0; e < E_; ++e) p[e] *= invs;
    int i1 = 0;
    for (int e = 1; e < E_; ++e) if (p[e] > p[i1]) i1 = e;   // first-occurrence max
    int i2 = (i1 == 0) ? 1 : 0;
    for (int e = 0; e < E_; ++e) if (e != i1 && p[e] > p[i2]) i2 = e;
    float w = p[i1] + p[i2];
    float ga = p[i1] / w, gb = p[i2] / w;
    sel_e[2 * n] = i1; sel_e[2 * n + 1] = i2;
    sel_g[2 * n] = ga; sel_g[2 * n + 1] = gb;
    gsum[n] = ga + gb;
    s_i1 = i1; s_i2 = i2; s_g1 = ga; s_g2 = gb;
    atomicAdd(&f_acc[i1], 1.0f);
    atomicAdd(&f_acc[i2], 1.0f);
    for (int e = 0; e < E_; ++e) atomicAdd(&p_acc[e], p[e]);
  }
  __syncthreads();
  int i1 = s_i1, i2 = s_i2; float ga = s_g1, gb = s_g2;
  for (int c = tid; c < C_; c += 64)
    K[(size_t)n * C_ + c] = ga * const2[i1 * C_ + c] + gb * const2[i2 * C_ + c];
}

// ---------------------------------------------------------------------------
// accumulate 24 bf16 lanes-worth from 3 dwordx4
// ---------------------------------------------------------------------------
__device__ __forceinline__ void acc24(uint4 u0, uint4 u1, uint4 u2, float* acc) {
  uint32_t us[12] = {u0.x, u0.y, u0.z, u0.w, u1.x, u1.y, u1.z, u1.w,
                     u2.x, u2.y, u2.z, u2.w};
  #pragma unroll
  for (int d = 0; d < 12; ++d) {
    acc[2 * d]     += __uint_as_float(us[d] << 16);
    acc[2 * d + 1] += __uint_as_float(us[d] & 0xffff0000u);
  }
}

// ---------------------------------------------------------------------------
// K3 (hot): one block per (n, h). Stage x row once (one barrier), then 28
// wave-independent tasks (expert k x position w): intra-wave ballot
// compaction into wave-private slist, dwordx4 row gather (lane owns 24
// outputs), threshold -> rare records. Fused combine write at the end.
// NO block barriers after staging.
// ---------------------------------------------------------------------------
__global__ __launch_bounds__(256) void k_main(
    const float* __restrict__ x, const __hip_bfloat16* __restrict__ w1t,
    const float* __restrict__ A, const float* __restrict__ Bc,
    const int* __restrict__ sel_e, const float* __restrict__ taus,
    const float* __restrict__ gsum, const float* __restrict__ K,
    float* __restrict__ out,
    int* __restrict__ rec, int* __restrict__ rec_count) {
  __shared__ float xs[14 * 385];   // xs[w*385 + c]
  __shared__ int slist[4][C_];     // wave-private spike lists
  int n = blockIdx.x, h = blockIdx.y;
  int tid = threadIdx.x;
  int lane = tid & 63, wave = tid >> 6;

  // stage x row h: xs[w*385 + c] = x[n, c, h, w]
  for (int idx = tid; idx < C_ * 14; idx += 256) {
    int c = idx / 14, w = idx - c * 14;
    xs[w * 385 + c] = x[((size_t)(n * C_ + c) * 14 + h) * 14 + w];
  }
  __syncthreads();   // the only block barrier

  int* sl = slist[wave];
  unsigned long long lmask = (1ull << lane) - 1ull;

  for (int t = wave; t < 28; t += 4) {
    int k = t / 14, w = t - k * 14;
    int pair = 2 * n + k;
    int e = sel_e[pair];
    float tau = taus[e];
    const uint4* wb = (const uint4*)(w1t + (size_t)e * C_ * HF_);  // 192 uint4/row
    const float4* Af = (const float4*)(A + e * HF_) + lane * 6;
    const float4* Bf = (const float4*)(Bc + e * HF_) + lane * 6;

    // wave-private spike list via ballot compaction (no atomics, no barrier)
    int nnz = 0;
    #pragma unroll
    for (int cb = 0; cb < 6; ++cb) {
      int c = cb * 64 + lane;
      bool sp = (xs[w * 385 + c] / tau - 1.0f >= 0.0f);  // s1 = spike(x/tau-1)
      unsigned long long m = __ballot(sp);
      if (sp) sl[nnz + __popcll(m & lmask)] = c;
      nnz += __popcll(m);
    }
    __asm__ volatile("s_waitcnt lgkmcnt(0)" ::: "memory");

    float acc[24];
    #pragma unroll
    for (int q = 0; q < 24; ++q) acc[q] = 0.f;

    int j = 0;
    for (; j + 2 <= nnz; j += 2) {               // 6 dwordx4 in flight
      const uint4* r0 = wb + sl[j] * 192 + lane * 3;
      const uint4* r1 = wb + sl[j + 1] * 192 + lane * 3;
      uint4 a0 = r0[0], a1 = r0[1], a2 = r0[2];
      uint4 b0 = r1[0], b1 = r1[1], b2 = r1[2];
      acc24(a0, a1, a2, acc);
      acc24(b0, b1, b2, acc);
    }
    if (j < nnz) {
      const uint4* r0 = wb + sl[j] * 192 + lane * 3;
      uint4 a0 = r0[0], a1 = r0[1], a2 = r0[2];
      acc24(a0, a1, a2, acc);
    }

    // threshold: spike2 iff A*S + B >= 0 (rare) ; lane owns o = lane*24+q
    #pragma unroll
    for (int q4 = 0; q4 < 6; ++q4) {
      float4 Av = Af[q4];
      float4 Bv = Bf[q4];
      float a0 = Av.x * acc[q4 * 4 + 0] + Bv.x;
      float a1 = Av.y * acc[q4 * 4 + 1] + Bv.y;
      float a2 = Av.z * acc[q4 * 4 + 2] + Bv.z;
      float a3 = Av.w * acc[q4 * 4 + 3] + Bv.w;
      #pragma unroll
      for (int qi = 0; qi < 4; ++qi) {
        float av = (qi == 0) ? a0 : (qi == 1) ? a1 : (qi == 2) ? a2 : a3;
        if (av >= 0.0f) {
          int ridx = atomicAdd(rec_count, 1);
          if (ridx < REC_CAP) {
            rec[ridx * 3 + 0] = pair;
            rec[ridx * 3 + 1] = h * 14 + w;
            rec[ridx * 3 + 2] = lane * 24 + q4 * 4 + qi;
          }
        }
      }
    }
  }

  // fused combine (xs is read-only now; no barrier needed)
  float g = gsum[n];
  for (int idx = tid; idx < C_ * 14; idx += 256) {
    int c = idx / 14, w = idx - c * 14;
    out[((size_t)(n * C_ + c) * 14 + h) * 14 + w] =
        g * xs[w * 385 + c] + K[(size_t)n * C_ + c];
  }
}

// ---------------------------------------------------------------------------
// K4: apply the rare layer-2 spike records; write aux
// ---------------------------------------------------------------------------
__global__ void k_apply(const int* __restrict__ rec, const int* __restrict__ rec_count,
                        const int* __restrict__ sel_e, const float* __restrict__ sel_g,
                        const float* __restrict__ inv2v, const float* __restrict__ w2,
                        const float* f_acc, const float* p_acc,
                        float* __restrict__ out, float* aux_out) {
  int nrec = *rec_count;
  if (nrec > REC_CAP) nrec = REC_CAP;
  for (int r = blockIdx.x; r < nrec; r += gridDim.x) {
    int pair = rec[r * 3], p = rec[r * 3 + 1], o = rec[r * 3 + 2];
    int n = pair >> 1;
    int e = sel_e[pair];
    float g = sel_g[pair];
    for (int c = threadIdx.x; c < C_; c += blockDim.x) {
      float wv = w2[(size_t)(e * C_ + c) * HF_ + o];
      atomicAdd(&out[(size_t)(n * C_ + c) * HW_ + p], g * inv2v[e * C_ + c] * wv);
    }
  }
  if (blockIdx.x == 0 && threadIdx.x == 0) {
    float s = 0.f;
    for (int e = 0; e < E_; ++e)
      s += (f_acc[e] * (1.0f / N_)) * (p_acc[e] * (1.0f / N_));
    *aux_out = 0.01f * E_ * s;
  }
}

// ---------------------------------------------------------------------------
extern "C" void kernel_launch(void* const* d_in, const int* in_sizes, int n_in,
                              void* d_out, int out_size, void* d_ws, size_t ws_size,
                              hipStream_t stream) {
  const float* x       = (const float*)d_in[0];
  const float* rw      = (const float*)d_in[1];
  const float* rb      = (const float*)d_in[2];
  const float* r_gamma = (const float*)d_in[3];
  const float* r_beta  = (const float*)d_in[4];
  const float* r_mean  = (const float*)d_in[5];
  const float* r_var   = (const float*)d_in[6];
  const float* w1      = (const float*)d_in[7];
  const float* b1      = (const float*)d_in[8];
  const float* g1      = (const float*)d_in[9];
  const float* be1     = (const float*)d_in[10];
  const float* m1      = (const float*)d_in[11];
  const float* v1      = (const float*)d_in[12];
  const float* w2      = (const float*)d_in[13];
  const float* b2      = (const float*)d_in[14];
  const float* g2      = (const float*)d_in[15];
  const float* be2     = (const float*)d_in[16];
  const float* m2      = (const float*)d_in[17];
  const float* v2      = (const float*)d_in[18];
  const float* taus    = (const float*)d_in[19];
  float* out = (float*)d_out;

  char* ws = (char*)d_ws;
  int*   header = (int*)ws;
  float* f_acc  = (float*)ws + 8;
  float* p_acc  = (float*)ws + 16;
  float* cnt    = (float*)(ws + 256);
  int*   sel_e  = (int*)(ws + 196864);
  float* sel_g  = (float*)(ws + 197888);
  float* gsum   = (float*)(ws + 198912);
  float* K      = (float*)(ws + 199424);
  float* A      = (float*)(ws + 396032);
  float* Bc     = (float*)(ws + 445184);
  float* const2 = (float*)(ws + 494336);
  float* inv2v  = (float*)(ws + 506624);
  int*   rec    = (int*)(ws + 518912);
  __hip_bfloat16* w1t = (__hip_bfloat16*)(ws + 715520);

  k_lifprep<<<LIFB + TRB + PRB, 256, 0, stream>>>(
      x, cnt, w1, w1t, b1, g1, be1, m1, v1, b2, g2, be2, m2, v2, taus,
      A, Bc, const2, inv2v, header);
  k_router<<<N_, 64, 0, stream>>>(cnt, rw, rb, r_gamma, r_beta, r_mean, r_var,
                                  const2, sel_e, sel_g, gsum, K, f_acc, p_acc);
  k_main<<<dim3(N_, 14), 256, 0, stream>>>(x, w1t, A, Bc, sel_e, taus,
                                           gsum, K, out, rec, header);
  k_apply<<<64, 128, 0, stream>>>(rec, header, sel_e, sel_g, inv2v, w2,
                                  f_acc, p_acc, out, out + (out_size - 1));
}